// Round 4
// baseline (206.650 us; speedup 1.0000x reference)
//
#include <hip/hip_runtime.h>
#include <hip/hip_bf16.h>
#include <hip/hip_fp16.h>
#include <math.h>

typedef _Float16 f16;
typedef _Float16 f16x8 __attribute__((ext_vector_type(8)));
typedef _Float16 f16x4 __attribute__((ext_vector_type(4)));
typedef _Float16 f16x2 __attribute__((ext_vector_type(2)));
typedef unsigned short u16x8v __attribute__((ext_vector_type(8)));
typedef float f32x4 __attribute__((ext_vector_type(4)));

namespace {
constexpr int B = 2;
constexpr int H = 16;
constexpr int S = 2048;
constexpr int D = 64;
constexpr int E = 1024;
// fold 1/sqrt(64) * log2(e) into Q so softmax uses exp2 directly
constexpr float QSCALE = 0.125f * 1.4426950408889634f;
}

#define GLOBAL_LOAD_LDS16(gp, lp)                                              \
  __builtin_amdgcn_global_load_lds(                                            \
      (const __attribute__((address_space(1))) void*)(gp),                     \
      (__attribute__((address_space(3))) void*)(lp), 16, 0, 0)

// ---------- prep: [blocks 0..1023] Wd fp32->f16 ; [blocks 1024..1039] Wkv = Wk*Wv, bkv = Wk*bv + bk
__global__ __launch_bounds__(256) void prep(const float* __restrict__ Wd, f16* __restrict__ wd16,
                                            const float* __restrict__ Wk, const float* __restrict__ Wv,
                                            const float* __restrict__ bv, const float* __restrict__ bk,
                                            float* __restrict__ Wkv, float* __restrict__ bkv) {
  if (blockIdx.x < 1024) {
    const int i = blockIdx.x * 256 + threadIdx.x;
    const float4 f = ((const float4*)Wd)[i];
    f16x4 o;
    o.x = (f16)f.x; o.y = (f16)f.y; o.z = (f16)f.z; o.w = (f16)f.w;
    *(f16x4*)(wd16 + 4 * (size_t)i) = o;
  } else {
    const int g = (blockIdx.x - 1024) * 256 + threadIdx.x;   // 0..4095
    const int i = g >> 6, j = g & 63;
    float s = 0.f;
#pragma unroll 16
    for (int d = 0; d < 64; ++d) s = fmaf(Wk[i * 64 + d], Wv[d * 64 + j], s);
    Wkv[g] = s;
    if (g < 64) {
      float bb = bk[g];
#pragma unroll 16
      for (int d = 0; d < 64; ++d) bb = fmaf(Wk[g * 64 + d], bv[d], bb);
      bkv[g] = bb;
    }
  }
}

// ---------- projections: blockIdx.y==0 -> Q; ==1 -> V then K (x loaded once, two weight passes).
__global__ __launch_bounds__(256) void proj3_mfma(const float* __restrict__ xq,
                                                  const float* __restrict__ xv,
                                                  const float* __restrict__ Wq,
                                                  const float* __restrict__ bq,
                                                  const float* __restrict__ Wv,
                                                  const float* __restrict__ bv,
                                                  const float* __restrict__ Wkv,
                                                  const float* __restrict__ bkv,
                                                  f16* __restrict__ qp,
                                                  f16* __restrict__ vp,
                                                  f16* __restrict__ kp) {
  const int which = blockIdx.y;
  const float* x = which ? xv : xq;

  const int t = threadIdx.x, lane = t & 63, w = t >> 6;
  const int l15 = lane & 15, quad = lane >> 4;
  const int m0 = (blockIdx.x * 4 + w) * 64;

  f16x8 af[4][2];
#pragma unroll
  for (int mt = 0; mt < 4; ++mt)
#pragma unroll
    for (int kc = 0; kc < 2; ++kc) {
      const float* g = x + (size_t)(m0 + mt * 16 + l15) * 64 + kc * 32 + quad * 8;
      const float4 a = *(const float4*)g, b2 = *(const float4*)(g + 4);
      f16x8 v;
      v[0]=(f16)a.x; v[1]=(f16)a.y; v[2]=(f16)a.z; v[3]=(f16)a.w;
      v[4]=(f16)b2.x; v[5]=(f16)b2.y; v[6]=(f16)b2.z; v[7]=(f16)b2.w;
      af[mt][kc] = v;
    }

  const int npass = which ? 2 : 1;
  for (int pass = 0; pass < npass; ++pass) {
    const float* W    = which ? (pass ? Wkv : Wv) : Wq;
    const float* bias = which ? (pass ? bkv : bv) : bq;
    f16* out          = which ? (pass ? kp : vp) : qp;
    const float scale = which ? 1.0f : QSCALE;

    f16x8 wf[4][2];
#pragma unroll
    for (int nt = 0; nt < 4; ++nt)
#pragma unroll
      for (int kc = 0; kc < 2; ++kc) {
        const float* g = W + (size_t)(nt * 16 + l15) * 64 + kc * 32 + quad * 8;
        const float4 a = *(const float4*)g, b2 = *(const float4*)(g + 4);
        f16x8 v;
        v[0]=(f16)a.x; v[1]=(f16)a.y; v[2]=(f16)a.z; v[3]=(f16)a.w;
        v[4]=(f16)b2.x; v[5]=(f16)b2.y; v[6]=(f16)b2.z; v[7]=(f16)b2.w;
        wf[nt][kc] = v;
      }

    f32x4 acc[4][4];   // [nt][mt]
#pragma unroll
    for (int nt = 0; nt < 4; ++nt)
#pragma unroll
      for (int mt = 0; mt < 4; ++mt) acc[nt][mt] = (f32x4){0.f, 0.f, 0.f, 0.f};
#pragma unroll
    for (int kc = 0; kc < 2; ++kc)
#pragma unroll
      for (int nt = 0; nt < 4; ++nt)
#pragma unroll
        for (int mt = 0; mt < 4; ++mt)
          acc[nt][mt] = __builtin_amdgcn_mfma_f32_16x16x32_f16(wf[nt][kc], af[mt][kc], acc[nt][mt], 0, 0, 0);

    float4 bl4[4];
#pragma unroll
    for (int nt = 0; nt < 4; ++nt) bl4[nt] = *(const float4*)&bias[nt * 16 + quad * 4];

#pragma unroll
    for (int mt = 0; mt < 4; ++mt) {
      const int g = m0 + mt * 16 + l15;   // (b*S+s)*H + h
      const int h = g & 15, bs_ = g >> 4;
      const int b = bs_ >> 11, s = bs_ & 2047;
      f16* o = out + ((size_t)(b * H + h) * S + s) * 64 + quad * 4;
#pragma unroll
      for (int nt = 0; nt < 4; ++nt) {
        const float p0 = (acc[nt][mt][0] + bl4[nt].x) * scale;
        const float p1 = (acc[nt][mt][1] + bl4[nt].y) * scale;
        const float p2 = (acc[nt][mt][2] + bl4[nt].z) * scale;
        const float p3 = (acc[nt][mt][3] + bl4[nt].w) * scale;
        union { f16x4 v4; f16x2 hh[2]; } u;
        u.hh[0] = __builtin_bit_cast(f16x2, __builtin_amdgcn_cvt_pkrtz(p0, p1));
        u.hh[1] = __builtin_bit_cast(f16x2, __builtin_amdgcn_cvt_pkrtz(p2, p3));
        *(f16x4*)(o + nt * 16) = u.v4;
      }
    }
  }
}

// ---------- MFMA flash attention v4: K direct global->register (no K LDS at all),
// in-register P (swapped QK^T + chosen V permutation), XOR-swizzled V tile,
// double-buffered K regs + V LDS, one raw barrier per tile, loop unrolled x2.
// V perm: phys col p holds V row kv(p) = (p>>5)*32 + ((p&7)>>2)*16 + ((p>>3)&3)*4 + (p&3).
// PV A-frag elem j (phys k = kc*32+quad*8+j) = P[q=l15][kv] = exp2(sc[2kc+(j>>2)][mt][j&3]).
__global__ __launch_bounds__(256) void attn_mfma(const f16* __restrict__ qp,
                                                 const f16* __restrict__ kp,
                                                 const f16* __restrict__ vp,
                                                 f16* __restrict__ ao) {
  __shared__ f16 vt[2][64 * 64];   // V^T tile [d][p], 16B-chunk XOR swizzle: chunk ^= d&7
  const int t = threadIdx.x, lane = t & 63, w = t >> 6;
  const int l15 = lane & 15, quad = lane >> 4;
  const int bh = blockIdx.x;
  const int q0 = blockIdx.y * 128;
  const f16* qbase = qp + ((size_t)bh * S + q0 + w * 32) * D;
  const f16* kbase = kp + (size_t)bh * S * D;
  const f16* vbase = vp + (size_t)bh * S * D;

  // V staging geometry
  const int vd0 = (t >> 5) * 8;                         // d block (8 rows of vt)
  const int p0 = (t & 31) * 2;                          // phys col pair
  const int vkv = ((p0 >> 5) << 5) | (((p0 & 7) >> 2) << 4) | (((p0 >> 3) & 3) << 2) | (p0 & 3);
  const int vchunk = p0 >> 3, vsub = p0 & 7;

  // K fragment base: lane reads row nt*16+l15, cols kc*32+quad*8 (contiguous 16B)
  const f16* kfbase = kbase + (size_t)l15 * D + quad * 8;

  f16x8 qf[2][2];
#pragma unroll
  for (int mt = 0; mt < 2; ++mt)
#pragma unroll
    for (int kc = 0; kc < 2; ++kc)
      qf[mt][kc] = *(const f16x8*)(qbase + (size_t)(mt * 16 + l15) * D + kc * 32 + quad * 8);

  // ones-column B-frag: B[k][n]=1 for n==0 -> row-sum (l) accumulates in O[mt][4] col 0
  f16x8 vb4;
#pragma unroll
  for (int j = 0; j < 8; ++j) vb4[j] = (l15 == 0) ? (f16)1.0f : (f16)0.0f;

  f32x4 O[2][5];
#pragma unroll
  for (int mt = 0; mt < 2; ++mt)
#pragma unroll
    for (int nt = 0; nt < 5; ++nt) O[mt][nt] = (f32x4){0.f, 0.f, 0.f, 0.f};

  // ---- prologue: K tile 0 -> kf[0]; V tile 0 -> regs -> vt[0]
  f16x8 kf[2][4][2];
#pragma unroll
  for (int nt = 0; nt < 4; ++nt)
#pragma unroll
    for (int kc = 0; kc < 2; ++kc)
      kf[0][nt][kc] = *(const f16x8*)(kfbase + (size_t)(nt * 16) * D + kc * 32);

  u16x8v va, vb2;
  {
    const f16* gv = vbase + (size_t)vkv * D + vd0;
    va  = *(const u16x8v*)gv;
    vb2 = *(const u16x8v*)(gv + D);
#pragma unroll
    for (int j = 0; j < 8; ++j) {
      const int d = vd0 + j;
      const unsigned pk = (unsigned)va[j] | ((unsigned)vb2[j] << 16);
      *(unsigned*)&vt[0][d * 64 + ((vchunk ^ (d & 7)) * 8) + vsub] = pk;
    }
  }

  for (int kt2 = 0; kt2 < S / 64; kt2 += 2) {
#pragma unroll
    for (int half = 0; half < 2; ++half) {
      const int kt = kt2 + half;
      // (A) prefetch next tile: K -> kf[half^1] regs, V -> va/vb2 regs
      if (kt + 1 < S / 64) {
        const f16* kn = kfbase + (size_t)((kt + 1) * 64) * D;
#pragma unroll
        for (int nt = 0; nt < 4; ++nt)
#pragma unroll
          for (int kc = 0; kc < 2; ++kc)
            kf[half ^ 1][nt][kc] = *(const f16x8*)(kn + (size_t)(nt * 16) * D + kc * 32);
        const f16* gv = vbase + ((size_t)(kt + 1) * 64 + vkv) * D + vd0;
        va  = *(const u16x8v*)gv;
        vb2 = *(const u16x8v*)(gv + D);
      }
      // (B) raw barrier: my ds_writes drained; vmcnt deliberately NOT drained
      __asm__ volatile("s_waitcnt lgkmcnt(0)" ::: "memory");
      __builtin_amdgcn_s_barrier();
      __asm__ volatile("" ::: "memory");

      // (C) QK^T swapped, all-register: sc[nt][mt] = mfma(K-frag, Q-frag) -> C[kv][q]
      f32x4 sc[4][2];
#pragma unroll
      for (int nt = 0; nt < 4; ++nt)
#pragma unroll
        for (int mt = 0; mt < 2; ++mt) sc[nt][mt] = (f32x4){0.f, 0.f, 0.f, 0.f};
      __builtin_amdgcn_s_setprio(1);
#pragma unroll
      for (int kc = 0; kc < 2; ++kc)
#pragma unroll
        for (int nt = 0; nt < 4; ++nt)
#pragma unroll
          for (int mt = 0; mt < 2; ++mt)
            sc[nt][mt] = __builtin_amdgcn_mfma_f32_16x16x32_f16(kf[half][nt][kc], qf[mt][kc], sc[nt][mt], 0, 0, 0);
      __builtin_amdgcn_s_setprio(0);

      // P = exp2(sc), packed straight into PV A-frags (in-register, no LDS)
      f16x8 pa[2][2];
#pragma unroll
      for (int mt = 0; mt < 2; ++mt)
#pragma unroll
        for (int kc = 0; kc < 2; ++kc) {
          const f32x4 s0 = sc[2 * kc][mt], s1 = sc[2 * kc + 1][mt];
          union { f16x8 v8; f16x2 h[4]; } u;
          u.h[0] = __builtin_bit_cast(f16x2, __builtin_amdgcn_cvt_pkrtz(
              __builtin_amdgcn_exp2f(s0[0]), __builtin_amdgcn_exp2f(s0[1])));
          u.h[1] = __builtin_bit_cast(f16x2, __builtin_amdgcn_cvt_pkrtz(
              __builtin_amdgcn_exp2f(s0[2]), __builtin_amdgcn_exp2f(s0[3])));
          u.h[2] = __builtin_bit_cast(f16x2, __builtin_amdgcn_cvt_pkrtz(
              __builtin_amdgcn_exp2f(s1[0]), __builtin_amdgcn_exp2f(s1[1])));
          u.h[3] = __builtin_bit_cast(f16x2, __builtin_amdgcn_cvt_pkrtz(
              __builtin_amdgcn_exp2f(s1[2]), __builtin_amdgcn_exp2f(s1[3])));
          pa[mt][kc] = u.v8;
        }

      // PV += P * V (phys-k order matches vt perm); l accumulates in O[mt][4] col 0
      __builtin_amdgcn_s_setprio(1);
#pragma unroll
      for (int kc = 0; kc < 2; ++kc) {
#pragma unroll
        for (int nt = 0; nt < 4; ++nt) {
          const f16x8 vbf = *(const f16x8*)&vt[half][(nt * 16 + l15) * 64 + (((kc * 4 + quad) ^ (l15 & 7)) * 8)];
#pragma unroll
          for (int mt = 0; mt < 2; ++mt)
            O[mt][nt] = __builtin_amdgcn_mfma_f32_16x16x32_f16(pa[mt][kc], vbf, O[mt][nt], 0, 0, 0);
        }
#pragma unroll
        for (int mt = 0; mt < 2; ++mt)
          O[mt][4] = __builtin_amdgcn_mfma_f32_16x16x32_f16(pa[mt][kc], vb4, O[mt][4], 0, 0, 0);
      }
      __builtin_amdgcn_s_setprio(0);

      // (D) write prefetched V tile kt+1 into vt[half^1]
      if (kt + 1 < S / 64) {
#pragma unroll
        for (int j = 0; j < 8; ++j) {
          const int d = vd0 + j;
          const unsigned pk = (unsigned)va[j] | ((unsigned)vb2[j] << 16);
          *(unsigned*)&vt[half ^ 1][d * 64 + ((vchunk ^ (d & 7)) * 8) + vsub] = pk;
        }
      }
    }
  }

  // epilogue: l lives in lane group's l15==0 lane of O[mt][4]
  const int b = bh >> 4, h = bh & 15;
#pragma unroll
  for (int mt = 0; mt < 2; ++mt)
#pragma unroll
    for (int r = 0; r < 4; ++r) {
      const float l = __shfl(O[mt][4][r], quad << 4, 64);
      const float inv = 1.f / l;
      const int row = q0 + w * 32 + mt * 16 + quad * 4 + r;
      f16* o = ao + ((size_t)b * S + row) * E + h * D;
#pragma unroll
      for (int nt = 0; nt < 4; ++nt)
        o[nt * 16 + l15] = (f16)(O[mt][nt][r] * inv);
    }
}

// ---------- dense: out[m][n] = sum_e A[m][e] * Wd16[n][e] + bd[n]
// BM=128, BN=64 -> grid (32,16)=512 blocks = 2 independent blocks/CU (2 waves/SIMD,
// cross-block overlap hides the per-K-step barrier drain). gload_lds width-16 with
// pre-swizzled global source + XOR-swizzled reads (conflict-free ds_read_b128).
__global__ __launch_bounds__(256) void dense_mfma(const f16* __restrict__ A,
                                                  const f16* __restrict__ Wd16,
                                                  const float* __restrict__ bd,
                                                  float* __restrict__ out) {
  __shared__ f16 as[2][128 * 64];
  __shared__ f16 bs[2][64 * 64];
  const int t = threadIdx.x;
  const int lane = t & 63;
  const int w = t >> 6;
  const int l15 = lane & 15;
  const int quad = lane >> 4;
  const int m0 = blockIdx.x * 128;
  const int n0 = blockIdx.y * 64;
  const int wm = (w >> 1) * 64, wn = (w & 1) * 32;   // wave tile 64x32

  // staging: lane l -> LDS row base+(l>>3), chunk l&7 (linear dest). Pre-swizzle the
  // GLOBAL chunk: (l&7) ^ (l>>3) so LDS[r][c] holds global chunk c ^ (r&7).
  const int srow = (lane >> 3);
  const int schunk = (lane & 7) ^ srow;
  const f16* ga0 = A    + (size_t)(m0 + w * 32 + srow) * E + schunk * 8;   // wave: 32 A rows
  const f16* gb0 = Wd16 + (size_t)(n0 + w * 16 + srow) * E + schunk * 8;   // wave: 16 B rows

  constexpr int NT = E / 64;

  f32x4 acc[4][2];
#pragma unroll
  for (int mt = 0; mt < 4; ++mt)
#pragma unroll
    for (int nt = 0; nt < 2; ++nt) acc[mt][nt] = (f32x4){0.f, 0.f, 0.f, 0.f};

#pragma unroll
  for (int i = 0; i < 4; ++i)
    GLOBAL_LOAD_LDS16(ga0 + (size_t)(i * 8) * E, &as[0][(w * 32 + i * 8) * 64]);
#pragma unroll
  for (int i = 0; i < 2; ++i)
    GLOBAL_LOAD_LDS16(gb0 + (size_t)(i * 8) * E, &bs[0][(w * 16 + i * 8) * 64]);
  __syncthreads();

  int cur = 0;
  for (int kt = 0; kt < NT; ++kt) {
    if (kt + 1 < NT) {
      const int nb = cur ^ 1;
#pragma unroll
      for (int i = 0; i < 4; ++i)
        GLOBAL_LOAD_LDS16(ga0 + (size_t)(i * 8) * E + (kt + 1) * 64, &as[nb][(w * 32 + i * 8) * 64]);
#pragma unroll
      for (int i = 0; i < 2; ++i)
        GLOBAL_LOAD_LDS16(gb0 + (size_t)(i * 8) * E + (kt + 1) * 64, &bs[nb][(w * 16 + i * 8) * 64]);
    }
    f16x8 af[4][2];
#pragma unroll
    for (int mt = 0; mt < 4; ++mt)
#pragma unroll
      for (int kc = 0; kc < 2; ++kc)
        af[mt][kc] = *(const f16x8*)&as[cur][(wm + mt * 16 + l15) * 64 + (((kc * 4 + quad) ^ (l15 & 7)) * 8)];
#pragma unroll
    for (int kc = 0; kc < 2; ++kc)
#pragma unroll
      for (int nt = 0; nt < 2; ++nt) {
        const f16x8 bf = *(const f16x8*)&bs[cur][(wn + nt * 16 + l15) * 64 + (((kc * 4 + quad) ^ (l15 & 7)) * 8)];
#pragma unroll
        for (int mt = 0; mt < 4; ++mt)
          acc[mt][nt] = __builtin_amdgcn_mfma_f32_16x16x32_f16(af[mt][kc], bf, acc[mt][nt], 0, 0, 0);
      }
    __syncthreads();
    cur ^= 1;
  }

#pragma unroll
  for (int nt = 0; nt < 2; ++nt) {
    const int col = n0 + wn + nt * 16 + l15;
    const float bdv = bd[col];
#pragma unroll
    for (int mt = 0; mt < 4; ++mt)
#pragma unroll
      for (int r = 0; r < 4; ++r)
        out[(size_t)(m0 + wm + mt * 16 + quad * 4 + r) * E + col] = acc[mt][nt][r] + bdv;
  }
}

extern "C" void kernel_launch(void* const* d_in, const int* in_sizes, int n_in,
                              void* d_out, int out_size, void* d_ws, size_t ws_size,
                              hipStream_t stream) {
  const float* queries = (const float*)d_in[0];
  const float* values  = (const float*)d_in[1];
  const float* Wv = (const float*)d_in[3];
  const float* bv = (const float*)d_in[4];
  const float* Wk = (const float*)d_in[5];
  const float* bk = (const float*)d_in[6];
  const float* Wq = (const float*)d_in[7];
  const float* bq = (const float*)d_in[8];
  const float* Wd = (const float*)d_in[9];
  const float* bd = (const float*)d_in[10];
  float* out = (float*)d_out;

  char* ws = (char*)d_ws;
  f16* qp    = (f16*)(ws);                          // 8 MB [B,H,S,D]
  f16* kp    = (f16*)(ws + 8u * 1024 * 1024);       // 8 MB
  f16* vp    = (f16*)(ws + 16u * 1024 * 1024);      // 8 MB
  f16* ao    = (f16*)(ws + 24u * 1024 * 1024);      // 8 MB [B,S,E]
  f16* wd16  = (f16*)(ws + 32u * 1024 * 1024);      // 2 MB
  float* wkv = (float*)(ws + 34u * 1024 * 1024);    // 16 KB
  float* bkv = (float*)(ws + 34u * 1024 * 1024 + 16384);
  (void)ws_size; (void)in_sizes; (void)n_in; (void)out_size;

  prep<<<1040, 256, 0, stream>>>(Wd, wd16, Wk, Wv, bv, bk, wkv, bkv);
  proj3_mfma<<<dim3(256, 2), 256, 0, stream>>>(queries, values, Wq, bq, Wv, bv, wkv, bkv, qp, vp, kp);
  attn_mfma<<<dim3(B * H, S / 128), 256, 0, stream>>>(qp, kp, vp, ao);
  dense_mfma<<<dim3(B * S / 128, E / 64), 256, 0, stream>>>(ao, wd16, bd, out);
}

// Round 5
// 183.954 us; speedup vs baseline: 1.1234x; 1.1234x over previous
//
#include <hip/hip_runtime.h>
#include <hip/hip_bf16.h>
#include <hip/hip_fp16.h>
#include <math.h>

typedef _Float16 f16;
typedef _Float16 f16x8 __attribute__((ext_vector_type(8)));
typedef _Float16 f16x4 __attribute__((ext_vector_type(4)));
typedef _Float16 f16x2 __attribute__((ext_vector_type(2)));
typedef unsigned short u16x8v __attribute__((ext_vector_type(8)));
typedef float f32x4 __attribute__((ext_vector_type(4)));

namespace {
constexpr int B = 2;
constexpr int H = 16;
constexpr int S = 2048;
constexpr int D = 64;
constexpr int E = 1024;
// fold 1/sqrt(64) * log2(e) into Q so softmax uses exp2 directly
constexpr float QSCALE = 0.125f * 1.4426950408889634f;
}

#define GLOBAL_LOAD_LDS16(gp, lp)                                              \
  __builtin_amdgcn_global_load_lds(                                            \
      (const __attribute__((address_space(1))) void*)(gp),                     \
      (__attribute__((address_space(3))) void*)(lp), 16, 0, 0)

// ---------- prep: [blocks 0..1023] Wd fp32->f16 ; [blocks 1024..1039] Wkv = Wk*Wv, bkv = Wk*bv + bk
__global__ __launch_bounds__(256) void prep(const float* __restrict__ Wd, f16* __restrict__ wd16,
                                            const float* __restrict__ Wk, const float* __restrict__ Wv,
                                            const float* __restrict__ bv, const float* __restrict__ bk,
                                            float* __restrict__ Wkv, float* __restrict__ bkv) {
  if (blockIdx.x < 1024) {
    const int i = blockIdx.x * 256 + threadIdx.x;
    const float4 f = ((const float4*)Wd)[i];
    f16x4 o;
    o.x = (f16)f.x; o.y = (f16)f.y; o.z = (f16)f.z; o.w = (f16)f.w;
    *(f16x4*)(wd16 + 4 * (size_t)i) = o;
  } else {
    const int g = (blockIdx.x - 1024) * 256 + threadIdx.x;   // 0..4095
    const int i = g >> 6, j = g & 63;
    float s = 0.f;
#pragma unroll 16
    for (int d = 0; d < 64; ++d) s = fmaf(Wk[i * 64 + d], Wv[d * 64 + j], s);
    Wkv[g] = s;
    if (g < 64) {
      float bb = bk[g];
#pragma unroll 16
      for (int d = 0; d < 64; ++d) bb = fmaf(Wk[g * 64 + d], bv[d], bb);
      bkv[g] = bb;
    }
  }
}

// ---------- projections: blockIdx.y==0 -> Q; ==1 -> V then K (x loaded once, two weight passes).
// Q/K outputs: [b][h][s][64] f16 (row-major per head).
// V output: TRANSPOSED + kv-permuted: vtp[b][h][d][S], column c holds V row
//   kv = perm(c&63) within each 64-tile: perm(p): kv5=p5,kv4=p2,kv3=p4,kv2=p3,kv1=p1,kv0=p0.
//   (this matches attn's PV fragment consumption so attn can stage V with global_load_lds)
__global__ __launch_bounds__(256) void proj3_mfma(const float* __restrict__ xq,
                                                  const float* __restrict__ xv,
                                                  const float* __restrict__ Wq,
                                                  const float* __restrict__ bq,
                                                  const float* __restrict__ Wv,
                                                  const float* __restrict__ bv,
                                                  const float* __restrict__ Wkv,
                                                  const float* __restrict__ bkv,
                                                  f16* __restrict__ qp,
                                                  f16* __restrict__ vtp,
                                                  f16* __restrict__ kp) {
  __shared__ f16 tb[16 * 16 * 64];   // 32 KB bounce: [h][d][s16] for V-pass transpose
  const int which = blockIdx.y;
  const float* x = which ? xv : xq;

  const int t = threadIdx.x, lane = t & 63, w = t >> 6;
  const int l15 = lane & 15, quad = lane >> 4;
  const int m0 = (blockIdx.x * 4 + w) * 64;

  f16x8 af[4][2];
#pragma unroll
  for (int mt = 0; mt < 4; ++mt)
#pragma unroll
    for (int kc = 0; kc < 2; ++kc) {
      const float* g = x + (size_t)(m0 + mt * 16 + l15) * 64 + kc * 32 + quad * 8;
      const float4 a = *(const float4*)g, b2 = *(const float4*)(g + 4);
      f16x8 v;
      v[0]=(f16)a.x; v[1]=(f16)a.y; v[2]=(f16)a.z; v[3]=(f16)a.w;
      v[4]=(f16)b2.x; v[5]=(f16)b2.y; v[6]=(f16)b2.z; v[7]=(f16)b2.w;
      af[mt][kc] = v;
    }

  const int npass = which ? 2 : 1;
  for (int pass = 0; pass < npass; ++pass) {
    const float* W    = which ? (pass ? Wkv : Wv) : Wq;
    const float* bias = which ? (pass ? bkv : bv) : bq;
    const bool vpass  = (which == 1) && (pass == 0);
    f16* out          = which ? (pass ? kp : (f16*)nullptr) : qp;
    const float scale = which ? 1.0f : QSCALE;

    f16x8 wf[4][2];
#pragma unroll
    for (int nt = 0; nt < 4; ++nt)
#pragma unroll
      for (int kc = 0; kc < 2; ++kc) {
        const float* g = W + (size_t)(nt * 16 + l15) * 64 + kc * 32 + quad * 8;
        const float4 a = *(const float4*)g, b2 = *(const float4*)(g + 4);
        f16x8 v;
        v[0]=(f16)a.x; v[1]=(f16)a.y; v[2]=(f16)a.z; v[3]=(f16)a.w;
        v[4]=(f16)b2.x; v[5]=(f16)b2.y; v[6]=(f16)b2.z; v[7]=(f16)b2.w;
        wf[nt][kc] = v;
      }

    f32x4 acc[4][4];   // [nt][mt]
#pragma unroll
    for (int nt = 0; nt < 4; ++nt)
#pragma unroll
      for (int mt = 0; mt < 4; ++mt) acc[nt][mt] = (f32x4){0.f, 0.f, 0.f, 0.f};
#pragma unroll
    for (int kc = 0; kc < 2; ++kc)
#pragma unroll
      for (int nt = 0; nt < 4; ++nt)
#pragma unroll
        for (int mt = 0; mt < 4; ++mt)
          acc[nt][mt] = __builtin_amdgcn_mfma_f32_16x16x32_f16(wf[nt][kc], af[mt][kc], acc[nt][mt], 0, 0, 0);

    float4 bl4[4];
#pragma unroll
    for (int nt = 0; nt < 4; ++nt) bl4[nt] = *(const float4*)&bias[nt * 16 + quad * 4];

    // lane holds: m = m0 + mt*16 + l15  -> h = l15, bs = (m0>>4)+mt
    //             n = nt*16 + quad*4 + r (out-dim d)
#pragma unroll
    for (int mt = 0; mt < 4; ++mt) {
      const int g = m0 + mt * 16 + l15;   // (b*S+s)*H + h
      const int h = g & 15, bs_ = g >> 4;
      const int b = bs_ >> 11, s = bs_ & 2047;
      f16* o = vpass ? nullptr : (out + ((size_t)(b * H + h) * S + s) * 64 + quad * 4);
#pragma unroll
      for (int nt = 0; nt < 4; ++nt) {
        const float p0 = (acc[nt][mt][0] + bl4[nt].x) * scale;
        const float p1 = (acc[nt][mt][1] + bl4[nt].y) * scale;
        const float p2 = (acc[nt][mt][2] + bl4[nt].z) * scale;
        const float p3 = (acc[nt][mt][3] + bl4[nt].w) * scale;
        union { f16x4 v4; f16x2 hh[2]; } u;
        u.hh[0] = __builtin_bit_cast(f16x2, __builtin_amdgcn_cvt_pkrtz(p0, p1));
        u.hh[1] = __builtin_bit_cast(f16x2, __builtin_amdgcn_cvt_pkrtz(p2, p3));
        if (vpass) {
          // tb[(h*64 + d)*16 + sl], h=l15, d=nt*16+quad*4+r, sl=w*4+mt
#pragma unroll
          for (int r = 0; r < 4; ++r)
            tb[(l15 * 64 + nt * 16 + quad * 4 + r) * 16 + w * 4 + mt] = u.v4[r];
        } else {
          *(f16x4*)(o + nt * 16) = u.v4;
        }
      }
    }

    if (vpass) {
      __syncthreads();
      // store V^T permuted: block covers 16 s (bs in [bx*16, bx*16+16)), 16 h, 64 d
      const int bsb = blockIdx.x * 16;
      const int bb = bsb >> 11;
      const int sb = bsb & 2047;
      const int off = sb & 63;                              // in {0,16,32,48}
      const int poff = (off & 32) | ((off & 16) >> 2);      // perm-inverse of the off bits
      const int col0 = (sb - off) + poff;
#pragma unroll
      for (int k2 = 0; k2 < 4; ++k2) {
        const int pi = t * 4 + k2;                          // (h,d) pair
        const int h = pi >> 6, d = pi & 63;
        const f16x8 lo = *(const f16x8*)&tb[pi * 16];
        const f16x8 hi = *(const f16x8*)&tb[pi * 16 + 8];
        f16* orow = vtp + ((size_t)(bb * H + h) * 64 + d) * S + col0;
        f16x4 g0, g1, g2, g3;
#pragma unroll
        for (int j = 0; j < 4; ++j) { g0[j]=lo[j]; g1[j]=lo[4+j]; g2[j]=hi[j]; g3[j]=hi[4+j]; }
        *(f16x4*)(orow + 0)  = g0;   // sl 0..3   -> cols poff+0..3
        *(f16x4*)(orow + 8)  = g1;   // sl 4..7   -> cols poff+8..11
        *(f16x4*)(orow + 16) = g2;   // sl 8..11  -> cols poff+16..19
        *(f16x4*)(orow + 24) = g3;   // sl 12..15 -> cols poff+24..27
      }
      __syncthreads();
    }
  }
}

// ---------- MFMA flash attention v5: K AND V staged via global_load_lds (V pre-transposed
// +permuted by proj), triple-buffered, counted vmcnt(4) + one raw barrier per tile.
// In-register P (swapped QK^T); XOR chunk swizzle via pre-swizzled GLOBAL source (rule #21).
// PV A-frag elem j (phys k = kc*32+quad*8+j) = P[q=l15][kv] = exp2(sc[2kc+(j>>2)][mt][j&3]).
__global__ __launch_bounds__(256) void attn_mfma(const f16* __restrict__ qp,
                                                 const f16* __restrict__ kp,
                                                 const f16* __restrict__ vtp,
                                                 f16* __restrict__ ao) {
  __shared__ f16 ks[3][64 * 64];   // K tile [kv][d-chunks], LDS[r][c] = global chunk c^(r&7)
  __shared__ f16 vs[3][64 * 64];   // V^T tile [d][p-chunks], same swizzle
  const int t = threadIdx.x, lane = t & 63, w = t >> 6;
  const int l15 = lane & 15, quad = lane >> 4;
  const int bh = blockIdx.x;
  const int q0 = blockIdx.y * 128;
  const f16* qbase = qp + ((size_t)bh * S + q0 + w * 32) * D;
  const f16* kbase = kp + (size_t)bh * S * D;
  const f16* vtbase = vtp + (size_t)bh * 64 * S;

  // staging geometry: chunk c = w*64 + lane (+256), row = c>>3, LDS chunk = c&7,
  // global chunk = (c&7) ^ (row&7) (pre-swizzled source, linear LDS dest)
  const int c1 = w * 64 + lane;
  const int row1 = c1 >> 3;
  const int sc1 = (c1 & 7) ^ (row1 & 7);          // row2 = row1+32: (row2&7)==(row1&7)
  const size_t koff1 = (size_t)row1 * D + sc1 * 8;
  const size_t koff2 = koff1 + (size_t)32 * D;
  const size_t voff1 = (size_t)row1 * S + sc1 * 8;
  const size_t voff2 = voff1 + (size_t)32 * S;

  f16x8 qf[2][2];
#pragma unroll
  for (int mt = 0; mt < 2; ++mt)
#pragma unroll
    for (int kc = 0; kc < 2; ++kc)
      qf[mt][kc] = *(const f16x8*)(qbase + (size_t)(mt * 16 + l15) * D + kc * 32 + quad * 8);

  // ones-column B-frag: B[k][n]=1 for n==0 -> row-sum (l) accumulates in O[mt][4] col 0
  f16x8 vb4;
#pragma unroll
  for (int j = 0; j < 8; ++j) vb4[j] = (l15 == 0) ? (f16)1.0f : (f16)0.0f;

  f32x4 O[2][5];
#pragma unroll
  for (int mt = 0; mt < 2; ++mt)
#pragma unroll
    for (int nt = 0; nt < 5; ++nt) O[mt][nt] = (f32x4){0.f, 0.f, 0.f, 0.f};

#define ISSUE_TILE(tt, buf)                                                    \
  {                                                                            \
    const f16* gk = kbase + (size_t)(tt) * (64 * D);                           \
    GLOBAL_LOAD_LDS16(gk + koff1, &ks[buf][w * 512]);                          \
    GLOBAL_LOAD_LDS16(gk + koff2, &ks[buf][2048 + w * 512]);                   \
    const f16* gv = vtbase + (size_t)(tt) * 64;                                \
    GLOBAL_LOAD_LDS16(gv + voff1, &vs[buf][w * 512]);                          \
    GLOBAL_LOAD_LDS16(gv + voff2, &vs[buf][2048 + w * 512]);                   \
  }

  // prologue: tiles 0,1 in flight
  ISSUE_TILE(0, 0);
  ISSUE_TILE(1, 1);

  int rb = 0;   // read buffer = kt%3
  for (int kt = 0; kt < S / 64; ++kt) {
    // (B) my tile-kt loads complete (4 newer stay in flight); barrier -> block-wide
    __asm__ volatile("s_waitcnt vmcnt(4)" ::: "memory");
    __builtin_amdgcn_s_barrier();
    __builtin_amdgcn_sched_barrier(0);

    // (A) issue tile kt+2 into buf (kt+2)%3 (clamped dummy keeps vmcnt uniform;
    //     safe: issued after the barrier that closes all reads of that buffer)
    {
      const int tt = (kt + 2 < S / 64) ? (kt + 2) : (S / 64 - 1);
      const int ib = (rb + 2 >= 3) ? (rb - 1) : (rb + 2);
      ISSUE_TILE(tt, ib);
    }

    // (C) QK^T swapped: sc[nt][mt] = mfma(K-frag, Q-frag) -> C[kv][q], q = l15 lane-local
    f32x4 sc[4][2];
#pragma unroll
    for (int nt = 0; nt < 4; ++nt)
#pragma unroll
      for (int mt = 0; mt < 2; ++mt) sc[nt][mt] = (f32x4){0.f, 0.f, 0.f, 0.f};
    __builtin_amdgcn_s_setprio(1);
#pragma unroll
    for (int kc = 0; kc < 2; ++kc)
#pragma unroll
      for (int nt = 0; nt < 4; ++nt) {
        const f16x8 kf = *(const f16x8*)&ks[rb][(nt * 16 + l15) * 64 + (((kc * 4 + quad) ^ (l15 & 7)) * 8)];
#pragma unroll
        for (int mt = 0; mt < 2; ++mt)
          sc[nt][mt] = __builtin_amdgcn_mfma_f32_16x16x32_f16(kf, qf[mt][kc], sc[nt][mt], 0, 0, 0);
      }
    __builtin_amdgcn_s_setprio(0);

    // P = exp2(sc), packed straight into PV A-frags (in-register, no LDS)
    f16x8 pa[2][2];
#pragma unroll
    for (int mt = 0; mt < 2; ++mt)
#pragma unroll
      for (int kc = 0; kc < 2; ++kc) {
        const f32x4 s0 = sc[2 * kc][mt], s1 = sc[2 * kc + 1][mt];
        union { f16x8 v8; f16x2 h[4]; } u;
        u.h[0] = __builtin_bit_cast(f16x2, __builtin_amdgcn_cvt_pkrtz(
            __builtin_amdgcn_exp2f(s0[0]), __builtin_amdgcn_exp2f(s0[1])));
        u.h[1] = __builtin_bit_cast(f16x2, __builtin_amdgcn_cvt_pkrtz(
            __builtin_amdgcn_exp2f(s0[2]), __builtin_amdgcn_exp2f(s0[3])));
        u.h[2] = __builtin_bit_cast(f16x2, __builtin_amdgcn_cvt_pkrtz(
            __builtin_amdgcn_exp2f(s1[0]), __builtin_amdgcn_exp2f(s1[1])));
        u.h[3] = __builtin_bit_cast(f16x2, __builtin_amdgcn_cvt_pkrtz(
            __builtin_amdgcn_exp2f(s1[2]), __builtin_amdgcn_exp2f(s1[3])));
        pa[mt][kc] = u.v8;
      }

    // PV += P * V (phys-k order matches vtp perm); l accumulates in O[mt][4] col 0
    __builtin_amdgcn_s_setprio(1);
#pragma unroll
    for (int kc = 0; kc < 2; ++kc) {
#pragma unroll
      for (int nt = 0; nt < 4; ++nt) {
        const f16x8 vbf = *(const f16x8*)&vs[rb][(nt * 16 + l15) * 64 + (((kc * 4 + quad) ^ (l15 & 7)) * 8)];
#pragma unroll
        for (int mt = 0; mt < 2; ++mt)
          O[mt][nt] = __builtin_amdgcn_mfma_f32_16x16x32_f16(pa[mt][kc], vbf, O[mt][nt], 0, 0, 0);
      }
#pragma unroll
      for (int mt = 0; mt < 2; ++mt)
        O[mt][4] = __builtin_amdgcn_mfma_f32_16x16x32_f16(pa[mt][kc], vb4, O[mt][4], 0, 0, 0);
    }
    __builtin_amdgcn_s_setprio(0);

    rb = (rb + 1 >= 3) ? 0 : rb + 1;
  }
#undef ISSUE_TILE

  // epilogue: l lives in lane group's l15==0 lane of O[mt][4]
  const int b = bh >> 4, h = bh & 15;
#pragma unroll
  for (int mt = 0; mt < 2; ++mt)
#pragma unroll
    for (int r = 0; r < 4; ++r) {
      const float l = __shfl(O[mt][4][r], quad << 4, 64);
      const float inv = 1.f / l;
      const int row = q0 + w * 32 + mt * 16 + quad * 4 + r;
      f16* o = ao + ((size_t)b * S + row) * E + h * D;
#pragma unroll
      for (int nt = 0; nt < 4; ++nt)
        o[nt * 16 + l15] = (f16)(O[mt][nt][r] * inv);
    }
}

// ---------- dense: out[m][n] = sum_e A[m][e] * Wd16[n][e] + bd[n]
// BM=128, BN=64 -> 512 blocks = 2 independent blocks/CU (cross-block overlap hides the
// per-K-step barrier drain). gload_lds width-16, pre-swizzled source + swizzled reads.
__global__ __launch_bounds__(256) void dense_mfma(const f16* __restrict__ A,
                                                  const f16* __restrict__ Wd16,
                                                  const float* __restrict__ bd,
                                                  float* __restrict__ out) {
  __shared__ f16 as[2][128 * 64];
  __shared__ f16 bs[2][64 * 64];
  const int t = threadIdx.x;
  const int lane = t & 63;
  const int w = t >> 6;
  const int l15 = lane & 15;
  const int quad = lane >> 4;
  const int m0 = blockIdx.x * 128;
  const int n0 = blockIdx.y * 64;
  const int wm = (w >> 1) * 64, wn = (w & 1) * 32;   // wave tile 64x32

  const int srow = (lane >> 3);
  const int schunk = (lane & 7) ^ srow;
  const f16* ga0 = A    + (size_t)(m0 + w * 32 + srow) * E + schunk * 8;   // wave: 32 A rows
  const f16* gb0 = Wd16 + (size_t)(n0 + w * 16 + srow) * E + schunk * 8;   // wave: 16 B rows

  constexpr int NT = E / 64;

  f32x4 acc[4][2];
#pragma unroll
  for (int mt = 0; mt < 4; ++mt)
#pragma unroll
    for (int nt = 0; nt < 2; ++nt) acc[mt][nt] = (f32x4){0.f, 0.f, 0.f, 0.f};

#pragma unroll
  for (int i = 0; i < 4; ++i)
    GLOBAL_LOAD_LDS16(ga0 + (size_t)(i * 8) * E, &as[0][(w * 32 + i * 8) * 64]);
#pragma unroll
  for (int i = 0; i < 2; ++i)
    GLOBAL_LOAD_LDS16(gb0 + (size_t)(i * 8) * E, &bs[0][(w * 16 + i * 8) * 64]);
  __syncthreads();

  int cur = 0;
  for (int kt = 0; kt < NT; ++kt) {
    if (kt + 1 < NT) {
      const int nb = cur ^ 1;
#pragma unroll
      for (int i = 0; i < 4; ++i)
        GLOBAL_LOAD_LDS16(ga0 + (size_t)(i * 8) * E + (kt + 1) * 64, &as[nb][(w * 32 + i * 8) * 64]);
#pragma unroll
      for (int i = 0; i < 2; ++i)
        GLOBAL_LOAD_LDS16(gb0 + (size_t)(i * 8) * E + (kt + 1) * 64, &bs[nb][(w * 16 + i * 8) * 64]);
    }
    f16x8 af[4][2];
#pragma unroll
    for (int mt = 0; mt < 4; ++mt)
#pragma unroll
      for (int kc = 0; kc < 2; ++kc)
        af[mt][kc] = *(const f16x8*)&as[cur][(wm + mt * 16 + l15) * 64 + (((kc * 4 + quad) ^ (l15 & 7)) * 8)];
#pragma unroll
    for (int kc = 0; kc < 2; ++kc)
#pragma unroll
      for (int nt = 0; nt < 2; ++nt) {
        const f16x8 bf = *(const f16x8*)&bs[cur][(wn + nt * 16 + l15) * 64 + (((kc * 4 + quad) ^ (l15 & 7)) * 8)];
#pragma unroll
        for (int mt = 0; mt < 4; ++mt)
          acc[mt][nt] = __builtin_amdgcn_mfma_f32_16x16x32_f16(af[mt][kc], bf, acc[mt][nt], 0, 0, 0);
      }
    __syncthreads();
    cur ^= 1;
  }

#pragma unroll
  for (int nt = 0; nt < 2; ++nt) {
    const int col = n0 + wn + nt * 16 + l15;
    const float bdv = bd[col];
#pragma unroll
    for (int mt = 0; mt < 4; ++mt)
#pragma unroll
      for (int r = 0; r < 4; ++r)
        out[(size_t)(m0 + wm + mt * 16 + quad * 4 + r) * E + col] = acc[mt][nt][r] + bdv;
  }
}

extern "C" void kernel_launch(void* const* d_in, const int* in_sizes, int n_in,
                              void* d_out, int out_size, void* d_ws, size_t ws_size,
                              hipStream_t stream) {
  const float* queries = (const float*)d_in[0];
  const float* values  = (const float*)d_in[1];
  const float* Wv = (const float*)d_in[3];
  const float* bv = (const float*)d_in[4];
  const float* Wk = (const float*)d_in[5];
  const float* bk = (const float*)d_in[6];
  const float* Wq = (const float*)d_in[7];
  const float* bq = (const float*)d_in[8];
  const float* Wd = (const float*)d_in[9];
  const float* bd = (const float*)d_in[10];
  float* out = (float*)d_out;

  char* ws = (char*)d_ws;
  f16* qp    = (f16*)(ws);                          // 8 MB [B,H,S,D]
  f16* kp    = (f16*)(ws + 8u * 1024 * 1024);       // 8 MB [B,H,S,D]
  f16* vtp   = (f16*)(ws + 16u * 1024 * 1024);      // 8 MB [B,H,D,S] permuted V^T
  f16* ao    = (f16*)(ws + 24u * 1024 * 1024);      // 8 MB [B,S,E]
  f16* wd16  = (f16*)(ws + 32u * 1024 * 1024);      // 2 MB
  float* wkv = (float*)(ws + 34u * 1024 * 1024);    // 16 KB
  float* bkv = (float*)(ws + 34u * 1024 * 1024 + 16384);
  (void)ws_size; (void)in_sizes; (void)n_in; (void)out_size;

  prep<<<1040, 256, 0, stream>>>(Wd, wd16, Wk, Wv, bv, bk, wkv, bkv);
  proj3_mfma<<<dim3(256, 2), 256, 0, stream>>>(queries, values, Wq, bq, Wv, bv, wkv, bkv, qp, vtp, kp);
  attn_mfma<<<dim3(B * H, S / 128), 256, 0, stream>>>(qp, kp, vtp, ao);
  dense_mfma<<<dim3(B * S / 128, E / 64), 256, 0, stream>>>(ao, wd16, bd, out);
}

// Round 6
// 175.471 us; speedup vs baseline: 1.1777x; 1.0483x over previous
//
#include <hip/hip_runtime.h>
#include <hip/hip_bf16.h>
#include <hip/hip_fp16.h>
#include <math.h>

typedef _Float16 f16;
typedef _Float16 f16x8 __attribute__((ext_vector_type(8)));
typedef _Float16 f16x4 __attribute__((ext_vector_type(4)));
typedef _Float16 f16x2 __attribute__((ext_vector_type(2)));
typedef unsigned short u16x8v __attribute__((ext_vector_type(8)));
typedef float f32x4 __attribute__((ext_vector_type(4)));

namespace {
constexpr int B = 2;
constexpr int H = 16;
constexpr int S = 2048;
constexpr int D = 64;
constexpr int E = 1024;
// fold 1/sqrt(64) * log2(e) into Q so softmax uses exp2 directly
constexpr float QSCALE = 0.125f * 1.4426950408889634f;
}

#define GLOBAL_LOAD_LDS16(gp, lp)                                              \
  __builtin_amdgcn_global_load_lds(                                            \
      (const __attribute__((address_space(1))) void*)(gp),                     \
      (__attribute__((address_space(3))) void*)(lp), 16, 0, 0)

// ---------- prep: [blocks 0..1023] Wd fp32->f16 ; [blocks 1024..1039] Wkv = Wk*Wv, bkv = Wk*bv + bk
__global__ __launch_bounds__(256) void prep(const float* __restrict__ Wd, f16* __restrict__ wd16,
                                            const float* __restrict__ Wk, const float* __restrict__ Wv,
                                            const float* __restrict__ bv, const float* __restrict__ bk,
                                            float* __restrict__ Wkv, float* __restrict__ bkv) {
  if (blockIdx.x < 1024) {
    const int i = blockIdx.x * 256 + threadIdx.x;
    const float4 f = ((const float4*)Wd)[i];
    f16x4 o;
    o.x = (f16)f.x; o.y = (f16)f.y; o.z = (f16)f.z; o.w = (f16)f.w;
    *(f16x4*)(wd16 + 4 * (size_t)i) = o;
  } else {
    const int g = (blockIdx.x - 1024) * 256 + threadIdx.x;   // 0..4095
    const int i = g >> 6, j = g & 63;
    float s = 0.f;
#pragma unroll 16
    for (int d = 0; d < 64; ++d) s = fmaf(Wk[i * 64 + d], Wv[d * 64 + j], s);
    Wkv[g] = s;
    if (g < 64) {
      float bb = bk[g];
#pragma unroll 16
      for (int d = 0; d < 64; ++d) bb = fmaf(Wk[g * 64 + d], bv[d], bb);
      bkv[g] = bb;
    }
  }
}

// ---------- projections: blockIdx.y==0 -> Q; ==1 -> V then K (x loaded once, two weight passes).
// Q/K outputs: [b][h][s][64] f16. V output: transposed+permuted vtp[b][h][d][S] (see R5 notes).
__global__ __launch_bounds__(256) void proj3_mfma(const float* __restrict__ xq,
                                                  const float* __restrict__ xv,
                                                  const float* __restrict__ Wq,
                                                  const float* __restrict__ bq,
                                                  const float* __restrict__ Wv,
                                                  const float* __restrict__ bv,
                                                  const float* __restrict__ Wkv,
                                                  const float* __restrict__ bkv,
                                                  f16* __restrict__ qp,
                                                  f16* __restrict__ vtp,
                                                  f16* __restrict__ kp) {
  __shared__ f16 tb[16 * 16 * 64];   // 32 KB bounce: [h][d][s16] for V-pass transpose
  const int which = blockIdx.y;
  const float* x = which ? xv : xq;

  const int t = threadIdx.x, lane = t & 63, w = t >> 6;
  const int l15 = lane & 15, quad = lane >> 4;
  const int m0 = (blockIdx.x * 4 + w) * 64;

  f16x8 af[4][2];
#pragma unroll
  for (int mt = 0; mt < 4; ++mt)
#pragma unroll
    for (int kc = 0; kc < 2; ++kc) {
      const float* g = x + (size_t)(m0 + mt * 16 + l15) * 64 + kc * 32 + quad * 8;
      const float4 a = *(const float4*)g, b2 = *(const float4*)(g + 4);
      f16x8 v;
      v[0]=(f16)a.x; v[1]=(f16)a.y; v[2]=(f16)a.z; v[3]=(f16)a.w;
      v[4]=(f16)b2.x; v[5]=(f16)b2.y; v[6]=(f16)b2.z; v[7]=(f16)b2.w;
      af[mt][kc] = v;
    }

  const int npass = which ? 2 : 1;
  for (int pass = 0; pass < npass; ++pass) {
    const float* W    = which ? (pass ? Wkv : Wv) : Wq;
    const float* bias = which ? (pass ? bkv : bv) : bq;
    const bool vpass  = (which == 1) && (pass == 0);
    f16* out          = which ? (pass ? kp : (f16*)nullptr) : qp;
    const float scale = which ? 1.0f : QSCALE;

    f16x8 wf[4][2];
#pragma unroll
    for (int nt = 0; nt < 4; ++nt)
#pragma unroll
      for (int kc = 0; kc < 2; ++kc) {
        const float* g = W + (size_t)(nt * 16 + l15) * 64 + kc * 32 + quad * 8;
        const float4 a = *(const float4*)g, b2 = *(const float4*)(g + 4);
        f16x8 v;
        v[0]=(f16)a.x; v[1]=(f16)a.y; v[2]=(f16)a.z; v[3]=(f16)a.w;
        v[4]=(f16)b2.x; v[5]=(f16)b2.y; v[6]=(f16)b2.z; v[7]=(f16)b2.w;
        wf[nt][kc] = v;
      }

    f32x4 acc[4][4];   // [nt][mt]
#pragma unroll
    for (int nt = 0; nt < 4; ++nt)
#pragma unroll
      for (int mt = 0; mt < 4; ++mt) acc[nt][mt] = (f32x4){0.f, 0.f, 0.f, 0.f};
#pragma unroll
    for (int kc = 0; kc < 2; ++kc)
#pragma unroll
      for (int nt = 0; nt < 4; ++nt)
#pragma unroll
        for (int mt = 0; mt < 4; ++mt)
          acc[nt][mt] = __builtin_amdgcn_mfma_f32_16x16x32_f16(wf[nt][kc], af[mt][kc], acc[nt][mt], 0, 0, 0);

    float4 bl4[4];
#pragma unroll
    for (int nt = 0; nt < 4; ++nt) bl4[nt] = *(const float4*)&bias[nt * 16 + quad * 4];

#pragma unroll
    for (int mt = 0; mt < 4; ++mt) {
      const int g = m0 + mt * 16 + l15;   // (b*S+s)*H + h
      const int h = g & 15, bs_ = g >> 4;
      const int b = bs_ >> 11, s = bs_ & 2047;
      f16* o = vpass ? nullptr : (out + ((size_t)(b * H + h) * S + s) * 64 + quad * 4);
#pragma unroll
      for (int nt = 0; nt < 4; ++nt) {
        const float p0 = (acc[nt][mt][0] + bl4[nt].x) * scale;
        const float p1 = (acc[nt][mt][1] + bl4[nt].y) * scale;
        const float p2 = (acc[nt][mt][2] + bl4[nt].z) * scale;
        const float p3 = (acc[nt][mt][3] + bl4[nt].w) * scale;
        union { f16x4 v4; f16x2 hh[2]; } u;
        u.hh[0] = __builtin_bit_cast(f16x2, __builtin_amdgcn_cvt_pkrtz(p0, p1));
        u.hh[1] = __builtin_bit_cast(f16x2, __builtin_amdgcn_cvt_pkrtz(p2, p3));
        if (vpass) {
#pragma unroll
          for (int r = 0; r < 4; ++r)
            tb[(l15 * 64 + nt * 16 + quad * 4 + r) * 16 + w * 4 + mt] = u.v4[r];
        } else {
          *(f16x4*)(o + nt * 16) = u.v4;
        }
      }
    }

    if (vpass) {
      __syncthreads();
      const int bsb = blockIdx.x * 16;
      const int bb = bsb >> 11;
      const int sb = bsb & 2047;
      const int off = sb & 63;                              // in {0,16,32,48}
      const int poff = (off & 32) | ((off & 16) >> 2);      // perm-inverse of the off bits
      const int col0 = (sb - off) + poff;
#pragma unroll
      for (int k2 = 0; k2 < 4; ++k2) {
        const int pi = t * 4 + k2;                          // (h,d) pair
        const int h = pi >> 6, d = pi & 63;
        const f16x8 lo = *(const f16x8*)&tb[pi * 16];
        const f16x8 hi = *(const f16x8*)&tb[pi * 16 + 8];
        f16* orow = vtp + ((size_t)(bb * H + h) * 64 + d) * S + col0;
        f16x4 g0, g1, g2, g3;
#pragma unroll
        for (int j = 0; j < 4; ++j) { g0[j]=lo[j]; g1[j]=lo[4+j]; g2[j]=hi[j]; g3[j]=hi[4+j]; }
        *(f16x4*)(orow + 0)  = g0;
        *(f16x4*)(orow + 8)  = g1;
        *(f16x4*)(orow + 16) = g2;
        *(f16x4*)(orow + 24) = g3;
      }
      __syncthreads();
    }
  }
}

// ---------- MFMA flash attention v6: 4-deep LDS buffers via global_load_lds; next tile's
// K-FRAGMENTS prefetched into registers during current tile's PV (removes ds_read latency
// + first-MFMA dependency from the per-tile critical path). Counted vmcnt(4), one raw
// barrier per tile (at tile END). In-register P (swapped QK^T), XOR chunk swizzle.
__global__ __launch_bounds__(256) void attn_mfma(const f16* __restrict__ qp,
                                                 const f16* __restrict__ kp,
                                                 const f16* __restrict__ vtp,
                                                 f16* __restrict__ ao) {
  __shared__ f16 ks[4][64 * 64];   // 32 KB: K tile [kv][d-chunks], LDS[r][c] = global chunk c^(r&7)
  __shared__ f16 vs[4][64 * 64];   // 32 KB: V^T tile [d][p-chunks], same swizzle
  const int t = threadIdx.x, lane = t & 63, w = t >> 6;
  const int l15 = lane & 15, quad = lane >> 4;
  const int bh = blockIdx.x;
  const int q0 = blockIdx.y * 128;
  const f16* qbase = qp + ((size_t)bh * S + q0 + w * 32) * D;
  const f16* kbase = kp + (size_t)bh * S * D;
  const f16* vtbase = vtp + (size_t)bh * 64 * S;

  // staging geometry: chunk c = w*64 + lane (+256), row = c>>3, LDS chunk = c&7,
  // global chunk = (c&7) ^ (row&7) (pre-swizzled source, linear LDS dest)
  const int c1 = w * 64 + lane;
  const int row1 = c1 >> 3;
  const int sc1 = (c1 & 7) ^ (row1 & 7);
  const size_t koff1 = (size_t)row1 * D + sc1 * 8;
  const size_t koff2 = koff1 + (size_t)32 * D;
  const size_t voff1 = (size_t)row1 * S + sc1 * 8;
  const size_t voff2 = voff1 + (size_t)32 * S;

  f16x8 qf[2][2];
#pragma unroll
  for (int mt = 0; mt < 2; ++mt)
#pragma unroll
    for (int kc = 0; kc < 2; ++kc)
      qf[mt][kc] = *(const f16x8*)(qbase + (size_t)(mt * 16 + l15) * D + kc * 32 + quad * 8);

  // ones-column B-frag: B[k][n]=1 for n==0 -> row-sum (l) accumulates in O[mt][4] col 0
  f16x8 vb4;
#pragma unroll
  for (int j = 0; j < 8; ++j) vb4[j] = (l15 == 0) ? (f16)1.0f : (f16)0.0f;

  f32x4 O[2][5];
#pragma unroll
  for (int mt = 0; mt < 2; ++mt)
#pragma unroll
    for (int nt = 0; nt < 5; ++nt) O[mt][nt] = (f32x4){0.f, 0.f, 0.f, 0.f};

#define ISSUE_TILE(tt, buf)                                                    \
  {                                                                            \
    const f16* gk = kbase + (size_t)(tt) * (64 * D);                           \
    GLOBAL_LOAD_LDS16(gk + koff1, &ks[buf][w * 512]);                          \
    GLOBAL_LOAD_LDS16(gk + koff2, &ks[buf][2048 + w * 512]);                   \
    const f16* gv = vtbase + (size_t)(tt) * 64;                                \
    GLOBAL_LOAD_LDS16(gv + voff1, &vs[buf][w * 512]);                          \
    GLOBAL_LOAD_LDS16(gv + voff2, &vs[buf][2048 + w * 512]);                   \
  }

  // K-frag read offsets (loop-invariant; buffer base added per use)
  int kofs[4][2];
#pragma unroll
  for (int nt = 0; nt < 4; ++nt)
#pragma unroll
    for (int kc = 0; kc < 2; ++kc)
      kofs[nt][kc] = (nt * 16 + l15) * 64 + (((kc * 4 + quad) ^ (l15 & 7)) * 8);

  f16x8 kfA[4][2], kfB[4][2];

  // prologue: tiles 0,1 in flight; wait tile 0; read its K-frags into kfA
  ISSUE_TILE(0, 0);
  ISSUE_TILE(1, 1);
  __asm__ volatile("s_waitcnt vmcnt(4)" ::: "memory");
  __builtin_amdgcn_s_barrier();
  __asm__ volatile("" ::: "memory");
#pragma unroll
  for (int nt = 0; nt < 4; ++nt)
#pragma unroll
    for (int kc = 0; kc < 2; ++kc) kfA[nt][kc] = *(const f16x8*)&ks[0][kofs[nt][kc]];

  auto STEP = [&](int kt, f16x8 (&kfc)[4][2], f16x8 (&kfn)[4][2]) {
    // entered with: barrier passed for kt, kfc = K-frags(kt) in regs, vs[kt&3] ready
    {  // issue tile kt+2 (clamped dummy keeps vmcnt uniform; target buf safe: 2 barriers old)
      const int tt = (kt + 2 < S / 64) ? (kt + 2) : (S / 64 - 1);
      ISSUE_TILE(tt, (kt + 2) & 3);
    }

    // QK^T swapped, pure-register: sc[nt][mt] = mfma(K, Q) -> C[kv][q], q = l15 lane-local
    f32x4 sc[4][2];
#pragma unroll
    for (int nt = 0; nt < 4; ++nt)
#pragma unroll
      for (int mt = 0; mt < 2; ++mt) sc[nt][mt] = (f32x4){0.f, 0.f, 0.f, 0.f};
    __builtin_amdgcn_s_setprio(1);
#pragma unroll
    for (int kc = 0; kc < 2; ++kc)
#pragma unroll
      for (int nt = 0; nt < 4; ++nt)
#pragma unroll
        for (int mt = 0; mt < 2; ++mt)
          sc[nt][mt] = __builtin_amdgcn_mfma_f32_16x16x32_f16(kfc[nt][kc], qf[mt][kc], sc[nt][mt], 0, 0, 0);
    __builtin_amdgcn_s_setprio(0);

    // P = exp2(sc) packed straight into PV A-frags (in-register)
    f16x8 pa[2][2];
#pragma unroll
    for (int mt = 0; mt < 2; ++mt)
#pragma unroll
      for (int kc = 0; kc < 2; ++kc) {
        const f32x4 s0 = sc[2 * kc][mt], s1 = sc[2 * kc + 1][mt];
        union { f16x8 v8; f16x2 h[4]; } u;
        u.h[0] = __builtin_bit_cast(f16x2, __builtin_amdgcn_cvt_pkrtz(
            __builtin_amdgcn_exp2f(s0[0]), __builtin_amdgcn_exp2f(s0[1])));
        u.h[1] = __builtin_bit_cast(f16x2, __builtin_amdgcn_cvt_pkrtz(
            __builtin_amdgcn_exp2f(s0[2]), __builtin_amdgcn_exp2f(s0[3])));
        u.h[2] = __builtin_bit_cast(f16x2, __builtin_amdgcn_cvt_pkrtz(
            __builtin_amdgcn_exp2f(s1[0]), __builtin_amdgcn_exp2f(s1[1])));
        u.h[3] = __builtin_bit_cast(f16x2, __builtin_amdgcn_cvt_pkrtz(
            __builtin_amdgcn_exp2f(s1[2]), __builtin_amdgcn_exp2f(s1[3])));
        pa[mt][kc] = u.v8;
      }

    // tile kt+1's loads complete (kt+2's stay in flight) -> prefetch its K-frags to regs
    __asm__ volatile("s_waitcnt vmcnt(4)" ::: "memory");
    {
      const f16* kb1 = &ks[(kt + 1) & 3][0];
#pragma unroll
      for (int nt = 0; nt < 4; ++nt)
#pragma unroll
        for (int kc = 0; kc < 2; ++kc) kfn[nt][kc] = *(const f16x8*)(kb1 + kofs[nt][kc]);
    }

    // PV += P * V; l accumulates in O[mt][4] col 0
    __builtin_amdgcn_s_setprio(1);
    const f16* vbuf = &vs[kt & 3][0];
#pragma unroll
    for (int kc = 0; kc < 2; ++kc) {
#pragma unroll
      for (int nt = 0; nt < 4; ++nt) {
        const f16x8 vbf = *(const f16x8*)(vbuf + kofs[nt][kc]);
#pragma unroll
        for (int mt = 0; mt < 2; ++mt)
          O[mt][nt] = __builtin_amdgcn_mfma_f32_16x16x32_f16(pa[mt][kc], vbf, O[mt][nt], 0, 0, 0);
      }
#pragma unroll
      for (int mt = 0; mt < 2; ++mt)
        O[mt][4] = __builtin_amdgcn_mfma_f32_16x16x32_f16(pa[mt][kc], vb4, O[mt][4], 0, 0, 0);
    }
    __builtin_amdgcn_s_setprio(0);

    // tile-end barrier (kfn reads may stay pending across it: their buffer isn't
    // overwritten until ISSUE(kt+3), one more barrier away)
    __builtin_amdgcn_s_barrier();
    __asm__ volatile("" ::: "memory");
  };

  for (int kt2 = 0; kt2 < S / 64; kt2 += 2) {
    STEP(kt2 + 0, kfA, kfB);
    STEP(kt2 + 1, kfB, kfA);
  }
#undef ISSUE_TILE

  // epilogue: l lives in lane group's l15==0 lane of O[mt][4]
  const int b = bh >> 4, h = bh & 15;
#pragma unroll
  for (int mt = 0; mt < 2; ++mt)
#pragma unroll
    for (int r = 0; r < 4; ++r) {
      const float l = __shfl(O[mt][4][r], quad << 4, 64);
      const float inv = 1.f / l;
      const int row = q0 + w * 32 + mt * 16 + quad * 4 + r;
      f16* o = ao + ((size_t)b * S + row) * E + h * D;
#pragma unroll
      for (int nt = 0; nt < 4; ++nt)
        o[nt * 16 + l15] = (f16)(O[mt][nt][r] * inv);
    }
}

// ---------- dense: out[m][n] = sum_e A[m][e] * Wd16[n][e] + bd[n]
// BM=128, BN=64, TRIPLE-buffered with counted vmcnt(6) + raw barrier (never drain to 0:
// 6 loads stay in flight across every barrier). 2 independent blocks/CU.
__global__ __launch_bounds__(256) void dense_mfma(const f16* __restrict__ A,
                                                  const f16* __restrict__ Wd16,
                                                  const float* __restrict__ bd,
                                                  float* __restrict__ out) {
  __shared__ f16 as[3][128 * 64];   // 48 KB
  __shared__ f16 bs[3][64 * 64];    // 24 KB
  const int t = threadIdx.x;
  const int lane = t & 63;
  const int w = t >> 6;
  const int l15 = lane & 15;
  const int quad = lane >> 4;
  const int m0 = blockIdx.x * 128;
  const int n0 = blockIdx.y * 64;
  const int wm = (w >> 1) * 64, wn = (w & 1) * 32;   // wave tile 64x32

  const int srow = (lane >> 3);
  const int schunk = (lane & 7) ^ srow;
  const f16* ga0 = A    + (size_t)(m0 + w * 32 + srow) * E + schunk * 8;   // wave: 32 A rows
  const f16* gb0 = Wd16 + (size_t)(n0 + w * 16 + srow) * E + schunk * 8;   // wave: 16 B rows

  constexpr int NT = E / 64;

#define ISSUE_D(tt, ib)                                                        \
  {                                                                            \
    _Pragma("unroll")                                                          \
    for (int i = 0; i < 4; ++i)                                                \
      GLOBAL_LOAD_LDS16(ga0 + (size_t)(i * 8) * E + (tt) * 64,                 \
                        &as[ib][(w * 32 + i * 8) * 64]);                       \
    _Pragma("unroll")                                                          \
    for (int i = 0; i < 2; ++i)                                                \
      GLOBAL_LOAD_LDS16(gb0 + (size_t)(i * 8) * E + (tt) * 64,                 \
                        &bs[ib][(w * 16 + i * 8) * 64]);                       \
  }

  f32x4 acc[4][2];
#pragma unroll
  for (int mt = 0; mt < 4; ++mt)
#pragma unroll
    for (int nt = 0; nt < 2; ++nt) acc[mt][nt] = (f32x4){0.f, 0.f, 0.f, 0.f};

  ISSUE_D(0, 0);
  ISSUE_D(1, 1);
  __asm__ volatile("s_waitcnt vmcnt(6)" ::: "memory");
  __builtin_amdgcn_s_barrier();
  __asm__ volatile("" ::: "memory");

  int rb = 0, ib = 2;   // read buffer kt%3, issue buffer (kt+2)%3
  for (int kt = 0; kt < NT; ++kt) {
    {  // issue tile kt+2 (clamped); buf is 2 barriers past its last reader
      const int tt = (kt + 2 < NT) ? (kt + 2) : (NT - 1);
      ISSUE_D(tt, ib);
    }
    f16x8 af[4][2];
#pragma unroll
    for (int mt = 0; mt < 4; ++mt)
#pragma unroll
      for (int kc = 0; kc < 2; ++kc)
        af[mt][kc] = *(const f16x8*)&as[rb][(wm + mt * 16 + l15) * 64 + (((kc * 4 + quad) ^ (l15 & 7)) * 8)];
#pragma unroll
    for (int kc = 0; kc < 2; ++kc)
#pragma unroll
      for (int nt = 0; nt < 2; ++nt) {
        const f16x8 bf = *(const f16x8*)&bs[rb][(wn + nt * 16 + l15) * 64 + (((kc * 4 + quad) ^ (l15 & 7)) * 8)];
#pragma unroll
        for (int mt = 0; mt < 4; ++mt)
          acc[mt][nt] = __builtin_amdgcn_mfma_f32_16x16x32_f16(af[mt][kc], bf, acc[mt][nt], 0, 0, 0);
      }
    // tile kt+1 landed (kt+2's 6 loads stay in flight across the barrier)
    __asm__ volatile("s_waitcnt vmcnt(6)" ::: "memory");
    __builtin_amdgcn_s_barrier();
    __asm__ volatile("" ::: "memory");
    rb = (rb + 1 >= 3) ? 0 : rb + 1;
    ib = (ib + 1 >= 3) ? 0 : ib + 1;
  }
#undef ISSUE_D

#pragma unroll
  for (int nt = 0; nt < 2; ++nt) {
    const int col = n0 + wn + nt * 16 + l15;
    const float bdv = bd[col];
#pragma unroll
    for (int mt = 0; mt < 4; ++mt)
#pragma unroll
      for (int r = 0; r < 4; ++r)
        out[(size_t)(m0 + wm + mt * 16 + quad * 4 + r) * E + col] = acc[mt][nt][r] + bdv;
  }
}

extern "C" void kernel_launch(void* const* d_in, const int* in_sizes, int n_in,
                              void* d_out, int out_size, void* d_ws, size_t ws_size,
                              hipStream_t stream) {
  const float* queries = (const float*)d_in[0];
  const float* values  = (const float*)d_in[1];
  const float* Wv = (const float*)d_in[3];
  const float* bv = (const float*)d_in[4];
  const float* Wk = (const float*)d_in[5];
  const float* bk = (const float*)d_in[6];
  const float* Wq = (const float*)d_in[7];
  const float* bq = (const float*)d_in[8];
  const float* Wd = (const float*)d_in[9];
  const float* bd = (const float*)d_in[10];
  float* out = (float*)d_out;

  char* ws = (char*)d_ws;
  f16* qp    = (f16*)(ws);                          // 8 MB [B,H,S,D]
  f16* kp    = (f16*)(ws + 8u * 1024 * 1024);       // 8 MB [B,H,S,D]
  f16* vtp   = (f16*)(ws + 16u * 1024 * 1024);      // 8 MB [B,H,D,S] permuted V^T
  f16* ao    = (f16*)(ws + 24u * 1024 * 1024);      // 8 MB [B,S,E]
  f16* wd16  = (f16*)(ws + 32u * 1024 * 1024);      // 2 MB
  float* wkv = (float*)(ws + 34u * 1024 * 1024);    // 16 KB
  float* bkv = (float*)(ws + 34u * 1024 * 1024 + 16384);
  (void)ws_size; (void)in_sizes; (void)n_in; (void)out_size;

  prep<<<1040, 256, 0, stream>>>(Wd, wd16, Wk, Wv, bv, bk, wkv, bkv);
  proj3_mfma<<<dim3(256, 2), 256, 0, stream>>>(queries, values, Wq, bq, Wv, bv, wkv, bkv, qp, vtp, kp);
  attn_mfma<<<dim3(B * H, S / 128), 256, 0, stream>>>(qp, kp, vtp, ao);
  dense_mfma<<<dim3(B * S / 128, E / 64), 256, 0, stream>>>(ao, wd16, bd, out);
}